// Round 2
// baseline (5829.755 us; speedup 1.0000x reference)
//
#include <hip/hip_runtime.h>
#include <hip/hip_bf16.h>

#define NN 100000
#define NP 160000
#define NE 320000
#define DH 256
#define DEPTH 3

typedef __attribute__((ext_vector_type(8))) short bf16x8;
typedef __attribute__((ext_vector_type(4))) float floatx4;
typedef __attribute__((ext_vector_type(4))) unsigned short ushx4;
typedef __attribute__((ext_vector_type(8))) unsigned short ushx8;

static __device__ __forceinline__ unsigned short f2bf(float f) {
    __hip_bfloat16 h = __float2bfloat16(f);
    return *reinterpret_cast<unsigned short*>(&h);
}

// ---------------- W f32 -> bf16 convert (all 3 layers, tiny) ----------------
__global__ void k_wconv(const float* __restrict__ W, unsigned short* __restrict__ Wb) {
    int idx = blockIdx.x * 256 + threadIdx.x;
    if (idx < DEPTH * DH * DH) Wb[idx] = f2bf(W[idx]);
}

// ---------------- H0 = V[src] + E ----------------
__global__ void k_init(const float* __restrict__ V, const float* __restrict__ E,
                       const int* __restrict__ src, float* __restrict__ H) {
    const int total = NE * (DH / 4);
    for (int idx = blockIdx.x * 256 + threadIdx.x; idx < total; idx += gridDim.x * 256) {
        int e = idx >> 6;
        int c = (idx & 63) << 2;
        int s = src[e];
        floatx4 v = *(const floatx4*)(V + s * DH + c);
        floatx4 ee = *(const floatx4*)(E + e * DH + c);
        *(floatx4*)(H + e * DH + c) = v + ee;
    }
}

// ---------------- scatter-add (optionally relu) H rows into M[idx[e]] ----------------
template <bool RELU>
__global__ void k_scatter(const float* __restrict__ H, const int* __restrict__ idxv,
                          float* __restrict__ M) {
    const int total = NE * (DH / 4);
    for (int idx = blockIdx.x * 256 + threadIdx.x; idx < total; idx += gridDim.x * 256) {
        int e = idx >> 6;
        int c = (idx & 63) << 2;
        int d = idxv[e];
        floatx4 h = *(const floatx4*)(H + e * DH + c);
        float* m = M + d * DH + c;
        if (RELU) {
            atomicAdd(m + 0, fmaxf(h.x, 0.f));
            atomicAdd(m + 1, fmaxf(h.y, 0.f));
            atomicAdd(m + 2, fmaxf(h.z, 0.f));
            atomicAdd(m + 3, fmaxf(h.w, 0.f));
        } else {
            atomicAdd(m + 0, h.x);
            atomicAdd(m + 1, h.y);
            atomicAdd(m + 2, h.z);
            atomicAdd(m + 3, h.w);
        }
    }
}

// ---------------- fused: Hout = Hin + (M[src] - relu(Hin[rev])) @ W^T + b ----------------
// 64-row tile, N=256 full, K=256 in 8 steps of 32. 4 waves: wave w owns cols [w*64, w*64+64).
__launch_bounds__(256)
__global__ void k_gemm(const float* __restrict__ Hin, const float* __restrict__ M,
                       const int* __restrict__ src, const int* __restrict__ rev,
                       const unsigned short* __restrict__ Wb, const float* __restrict__ bias,
                       float* __restrict__ Hout) {
    // A tile: 64 rows x 256 cols bf16, row pitch 264 (+8 pad -> bank spread)
    __shared__ unsigned short Alds[64][264];
    // W k-slice: [col=256][k=32] bf16, pitch 40 (80B -> bank spread)
    __shared__ unsigned short Wlds[256][40];

    const int tid = threadIdx.x;
    const int w = tid >> 6;
    const int lane = tid & 63;
    const int row0 = blockIdx.x * 64;

    // ---- stage A = M[src] - relu(Hin[rev]) as bf16 ----
    {
        const int rbase = tid >> 6;       // wave id: rows rbase, rbase+4, ...
        const int c = (tid & 63) * 4;     // 4 cols per thread
        #pragma unroll 4
        for (int it = 0; it < 16; ++it) {
            int rr = it * 4 + rbase;
            int e = row0 + rr;
            int s = src[e];
            int rv = rev[e];
            floatx4 m = *(const floatx4*)(M + s * DH + c);
            floatx4 h = *(const floatx4*)(Hin + rv * DH + c);
            ushx4 a;
            a.x = f2bf(m.x - fmaxf(h.x, 0.f));
            a.y = f2bf(m.y - fmaxf(h.y, 0.f));
            a.z = f2bf(m.z - fmaxf(h.z, 0.f));
            a.w = f2bf(m.w - fmaxf(h.w, 0.f));
            *(ushx4*)&Alds[rr][c] = a;
        }
    }

    floatx4 acc[4][4];
    #pragma unroll
    for (int m = 0; m < 4; ++m)
        #pragma unroll
        for (int n = 0; n < 4; ++n)
            acc[m][n] = (floatx4){0.f, 0.f, 0.f, 0.f};

    const int rsel = lane & 15;
    const int kq = lane >> 4;   // 0..3, k-offset = kq*8

    #pragma unroll 1
    for (int ks = 0; ks < 8; ++ks) {
        __syncthreads();  // prev-iter Wlds reads done; (ks=0) also pairs with next barrier for Alds
        // stage W slice: thread t stages col t (32 bf16 = 64B contiguous from global)
        {
            const unsigned short* wg = Wb + tid * DH + ks * 32;
            #pragma unroll
            for (int j = 0; j < 4; ++j)
                *(ushx8*)&Wlds[tid][j * 8] = *(const ushx8*)(wg + j * 8);
        }
        __syncthreads();

        bf16x8 afrag[4], bfrag[4];
        #pragma unroll
        for (int m = 0; m < 4; ++m)
            afrag[m] = *(const bf16x8*)&Alds[m * 16 + rsel][ks * 32 + kq * 8];
        #pragma unroll
        for (int n = 0; n < 4; ++n)
            bfrag[n] = *(const bf16x8*)&Wlds[w * 64 + n * 16 + rsel][kq * 8];
        #pragma unroll
        for (int m = 0; m < 4; ++m)
            #pragma unroll
            for (int n = 0; n < 4; ++n)
                acc[m][n] = __builtin_amdgcn_mfma_f32_16x16x32_bf16(afrag[m], bfrag[n], acc[m][n], 0, 0, 0);
    }

    // ---- epilogue: Hout = Hin + acc + bias ----
    // C/D layout: col = lane&15, row = (lane>>4)*4 + reg   [m89-verified]
    #pragma unroll
    for (int m = 0; m < 4; ++m)
        #pragma unroll
        for (int n = 0; n < 4; ++n)
            #pragma unroll
            for (int r4 = 0; r4 < 4; ++r4) {
                int rr = m * 16 + kq * 4 + r4;
                int cc = w * 64 + n * 16 + rsel;
                int gi = (row0 + rr) * DH + cc;
                Hout[gi] = Hin[gi] + acc[m][n][r4] + bias[cc];
            }
}

extern "C" void kernel_launch(void* const* d_in, const int* in_sizes, int n_in,
                              void* d_out, int out_size, void* d_ws, size_t ws_size,
                              hipStream_t stream) {
    const float* V = (const float*)d_in[0];
    const float* E = (const float*)d_in[1];
    const float* W = (const float*)d_in[2];
    const float* b = (const float*)d_in[3];
    const int* edge = (const int*)d_in[4];
    const int* rev = (const int*)d_in[5];
    const int* src = edge;
    const int* dest = edge + NE;

    float* outV = (float*)d_out;                       // NN*DH floats
    float* outH = (float*)d_out + (size_t)NN * DH;     // NE*DH floats

    float* wsH = (float*)d_ws;                                          // NE*DH f32
    unsigned short* Wb = (unsigned short*)((char*)d_ws + (size_t)NE * DH * 4);  // DEPTH*DH*DH bf16

    float* Mbuf = outV;  // reuse V_out region as M scratch during layers

    k_wconv<<<(DEPTH * DH * DH + 255) / 256, 256, 0, stream>>>(W, Wb);
    k_init<<<2048, 256, 0, stream>>>(V, E, src, wsH);

    float* Hcur = wsH;
    float* Hnext = outH;
    for (int l = 0; l < DEPTH; ++l) {
        hipMemsetAsync(Mbuf, 0, (size_t)NN * DH * sizeof(float), stream);
        k_scatter<true><<<2048, 256, 0, stream>>>(Hcur, dest, Mbuf);
        k_gemm<<<NE / 64, 256, 0, stream>>>(Hcur, Mbuf, src, rev,
                                            Wb + l * DH * DH, b + l * DH, Hnext);
        float* t = Hcur; Hcur = Hnext; Hnext = t;
    }
    // after 3 swaps Hcur == outH (final H already in place)

    hipMemsetAsync(outV, 0, (size_t)NN * DH * sizeof(float), stream);
    k_scatter<false><<<2048, 256, 0, stream>>>(Hcur, src, outV);
}